// Round 8
// baseline (11832.264 us; speedup 1.0000x reference)
//
#include <hip/hip_runtime.h>
#include <hip/hip_cooperative_groups.h>

namespace cg = cooperative_groups;

#define M_ROWS 2048
#define N_COLS 4096
#define RHO_C 1.0f
#define STEP_C 5e-05f
#define MAX_ITERS_C 100
#define INNER_C 20

// Relaxed agent-scope atomics: coherent at the Infinity Cache (sc1 path).
// Session law (R1-R7): arrival RMWs spread; polled line gets exactly ONE
// write/round; data exchange read-once agent-scope; pollers s_sleep-backoff.
// R8 lever: leaf arrivals are per-XCD (real XCC_ID) with WORKGROUP-scope
// RMWs -> executed in the XCD-local L2 (no sc1), removing one MALL RT from
// the notify chain. Only the 8 XCD completers touch the MALL (root->epoch).
__device__ __forceinline__ float aload(const float* p) {
    return __hip_atomic_load(p, __ATOMIC_RELAXED, __HIP_MEMORY_SCOPE_AGENT);
}
__device__ __forceinline__ void astore(float* p, float v) {
    __hip_atomic_store(p, v, __ATOMIC_RELAXED, __HIP_MEMORY_SCOPE_AGENT);
}
__device__ __forceinline__ float2 aload2(const float* p) {
    unsigned long long v = __hip_atomic_load(
        (const unsigned long long*)p, __ATOMIC_RELAXED,
        __HIP_MEMORY_SCOPE_AGENT);
    union { unsigned long long u; float2 f; } c; c.u = v; return c.f;
}
__device__ __forceinline__ unsigned aldu(const unsigned* p) {
    return __hip_atomic_load(p, __ATOMIC_RELAXED, __HIP_MEMORY_SCOPE_AGENT);
}

// Notify+wait chain, called by thread 0 ONLY, after producers (all in
// wave 0) issued their agent-scope stores. vmcnt(0) drains the whole
// wave's stores (release). Leaf = per-XCD line, workgroup-scope RMW
// (L2-local; all accessors are same-XCD by construction). Census-based
// targets make completer detection correct for ANY block->XCD layout.
// Root gets <=8 agent RMWs/round; epoch gets exactly 1 and is the only
// polled line (quiet regime). Monotonic counters, no resets.
__device__ __forceinline__ void chain_notify_wait(
    unsigned* bs, unsigned xcc, unsigned leafT, unsigned rootT, unsigned n)
{
    asm volatile("s_waitcnt vmcnt(0)" ::: "memory");
    unsigned old = __hip_atomic_fetch_add(bs + (xcc << 5), 1u,
                       __ATOMIC_RELAXED, __HIP_MEMORY_SCOPE_WORKGROUP);
    if (old == n * leafT + (leafT - 1u)) {
        unsigned ro = __hip_atomic_fetch_add(bs + 256, 1u,
                          __ATOMIC_RELAXED, __HIP_MEMORY_SCOPE_AGENT);
        if (ro == n * rootT + (rootT - 1u))
            __hip_atomic_fetch_add(bs + 288, 1u, __ATOMIC_RELAXED,
                                   __HIP_MEMORY_SCOPE_AGENT);
    }
    while (aldu(bs + 288) <= n)
        __builtin_amdgcn_s_sleep(1);
    asm volatile("" ::: "memory");
}

// 256 blocks (1/CU) x 1024 threads (16 waves), persistent cooperative kernel.
// Gram form: g = c + rho*(M x - A^T rt), M = A^T A held ENTIRELY in registers:
// wave w = (cgp=w>>2, rq=w&3); thread (cgp,rq,lane):
//   accM[r][4q+e] = M[16*blk + 4*rq + r][1024*cgp + 256*q + 4*lane + e]
// Block b also owns rows [8b,8b+8) of A (Ax/s,u,rt) and x entries [16b,16b+16).
//
// Per grid round (3 block syncs, was 4):
//   [inner!=0] stage x -> xs4, sync
//   FMA + shuffle reduce -> red, sync
//   producers (wave 0) compute + agent-store; thread0: drain + chain; sync
__global__ __launch_bounds__(1024) void admm_xcd(
    const float* __restrict__ A, const float* __restrict__ bvec,
    const float* __restrict__ cvec, float* __restrict__ out,
    float* __restrict__ x0, float* __restrict__ x1,
    float* __restrict__ rt, unsigned* __restrict__ bstate)
{
    cg::grid_group grid = cg::this_grid();
    const int tid  = threadIdx.x;
    const int blk  = blockIdx.x;
    const int lane = tid & 63;
    const int wave = tid >> 6;
    const int cgp  = wave >> 2;   // col-group: cols [1024*cgp, +1024)
    const int rq   = wave & 3;    // row-quad : rows 16*blk + 4*rq .. +4

    // physical XCD of this block (HW-verified readable on gfx950)
    unsigned xcc;
    asm volatile("s_getreg_b32 %0, hwreg(HW_REG_XCC_ID)" : "=s"(xcc));
    xcc &= 7u;

    __shared__ float  abuf[4 * N_COLS];  // 64 KB staging (A rows / rt)
    __shared__ float4 xs4[1024];         // 16 KB staged x (and Ax-phase x)
    __shared__ float  red[4][16];        // per-colgroup row partials
    __shared__ float4 gred[64];          // w-phase reduce scratch
    __shared__ float  wl[16], cw[16];
    __shared__ float  sv[8], uv[8], tpart[16];

    float* xs = reinterpret_cast<float*>(xs4);
    const float4* A4 = reinterpret_cast<const float4*>(A);
    float4* abuf4 = reinterpret_cast<float4*>(abuf);

    // ---- init ----
    if (tid < 16) {
        cw[tid] = cvec[blk * 16 + tid];
        astore(&x0[blk * 16 + tid], 0.0f);
    }
    if (tid < 8) {
        sv[tid] = 0.0f; uv[tid] = 0.0f;
        astore(&rt[blk * 8 + tid], bvec[blk * 8 + tid]);
    }
    // bstate: leaves [xcc*32] xcc<8 | root [256] | epoch [288] | census [320..327]
    if (blk == 0 && tid < 512) bstate[tid] = 0u;

    // ---- precompute register-resident M fragment ----
    float accM[4][16];
    #pragma unroll
    for (int r = 0; r < 4; ++r)
        #pragma unroll
        for (int k = 0; k < 16; ++k) accM[r][k] = 0.0f;

    for (int i0 = 0; i0 < M_ROWS; i0 += 4) {
        #pragma unroll
        for (int ii = 0; ii < 4; ++ii)
            abuf4[ii * 1024 + tid] = A4[(size_t)(i0 + ii) * 1024 + tid];
        __syncthreads();
        #pragma unroll
        for (int ii = 0; ii < 4; ++ii) {
            const float*  row  = abuf + ii * N_COLS;
            const float4* row4 = abuf4 + ii * 1024;
            float4 av[4];
            #pragma unroll
            for (int q = 0; q < 4; ++q)
                av[q] = row4[256 * cgp + 64 * q + lane];
            float cb[4];
            #pragma unroll
            for (int r = 0; r < 4; ++r) cb[r] = row[blk * 16 + rq * 4 + r];
            #pragma unroll
            for (int r = 0; r < 4; ++r)
                #pragma unroll
                for (int q = 0; q < 4; ++q) {
                    accM[r][4 * q + 0] = fmaf(cb[r], av[q].x, accM[r][4 * q + 0]);
                    accM[r][4 * q + 1] = fmaf(cb[r], av[q].y, accM[r][4 * q + 1]);
                    accM[r][4 * q + 2] = fmaf(cb[r], av[q].z, accM[r][4 * q + 2]);
                    accM[r][4 * q + 3] = fmaf(cb[r], av[q].w, accM[r][4 * q + 3]);
                }
        }
        __syncthreads();
    }

    grid.sync();   // publishes x0/rt + zeroed bstate

    // ---- XCD census (deadlock-proof completer thresholds) ----
    if (tid == 0)
        __hip_atomic_fetch_add(&bstate[320 + xcc], 1u, __ATOMIC_RELAXED,
                               __HIP_MEMORY_SCOPE_AGENT);
    grid.sync();   // census visible grid-wide
    unsigned leafT = 1u, rootT = 1u;   // used by thread 0 only
    if (tid == 0) {
        rootT = 0u;
        #pragma unroll
        for (int k = 0; k < 8; ++k) {
            unsigned c = aldu(&bstate[320 + k]);
            if (k == (int)xcc) leafT = c;
            rootT += (c != 0u) ? 1u : 0u;
        }
    }

    // ---- initial x@0 stage (inner-0 of each outer reuses prior stage) ----
    {
        float2 lo = aload2(x0 + 4 * tid);
        float2 hi = aload2(x0 + 4 * tid + 2);
        xs4[tid] = make_float4(lo.x, lo.y, hi.x, hi.y);
    }
    __syncthreads();

    unsigned bar_n = 0;

    for (int outer = 0; outer < MAX_ITERS_C; ++outer) {
        // ---- w-phase (block-local result): wl = (A^T rt)[16b..16b+16) ----
        abuf[tid]        = aload(&rt[tid]);
        abuf[tid + 1024] = aload(&rt[tid + 1024]);
        __syncthreads();
        {
            const int p = tid >> 2, gq = tid & 3;
            float4 acc = {0.f, 0.f, 0.f, 0.f};
            #pragma unroll
            for (int k2 = 0; k2 < 8; ++k2) {
                const int i = p + 256 * k2;
                const float tv = abuf[i];
                float4 a = A4[(size_t)i * 1024 + blk * 4 + gq];
                acc.x = fmaf(a.x, tv, acc.x); acc.y = fmaf(a.y, tv, acc.y);
                acc.z = fmaf(a.z, tv, acc.z); acc.w = fmaf(a.w, tv, acc.w);
            }
            #pragma unroll
            for (int off = 4; off < 64; off <<= 1) {
                acc.x += __shfl_xor(acc.x, off);
                acc.y += __shfl_xor(acc.y, off);
                acc.z += __shfl_xor(acc.z, off);
                acc.w += __shfl_xor(acc.w, off);
            }
            if ((lane >> 2) == 0) gred[wave * 4 + gq] = acc;
        }
        __syncthreads();
        if (tid < 4) {
            float4 tot = {0.f, 0.f, 0.f, 0.f};
            #pragma unroll
            for (int w = 0; w < 16; ++w) {
                float4 v = gred[w * 4 + tid];
                tot.x += v.x; tot.y += v.y; tot.z += v.z; tot.w += v.w;
            }
            wl[tid * 4 + 0] = tot.x; wl[tid * 4 + 1] = tot.y;
            wl[tid * 4 + 2] = tot.z; wl[tid * 4 + 3] = tot.w;
        }
        __syncthreads();

        // ---- inner PGD: x <- relu(x - step*(c + rho*(Mx - wl))) ----
        for (int inner = 0; inner < INNER_C; ++inner) {
            const float* xsrc = (inner & 1) ? x1 : x0;
            float*       xdst = (inner & 1) ? x0 : x1;

            if (inner != 0) {   // inner 0: xs4 already holds current x
                float2 lo = aload2(xsrc + 4 * tid);
                float2 hi = aload2(xsrc + 4 * tid + 2);
                xs4[tid] = make_float4(lo.x, lo.y, hi.x, hi.y);
                __syncthreads();               // (A) xs4 staged
            }

            float4 xq[4];
            #pragma unroll
            for (int q = 0; q < 4; ++q)
                xq[q] = xs4[256 * cgp + 64 * q + lane];

            float4 pd = {0.f, 0.f, 0.f, 0.f};
            #pragma unroll
            for (int q = 0; q < 4; ++q) {
                pd.x = fmaf(accM[0][4*q+0], xq[q].x, pd.x);
                pd.x = fmaf(accM[0][4*q+1], xq[q].y, pd.x);
                pd.x = fmaf(accM[0][4*q+2], xq[q].z, pd.x);
                pd.x = fmaf(accM[0][4*q+3], xq[q].w, pd.x);
                pd.y = fmaf(accM[1][4*q+0], xq[q].x, pd.y);
                pd.y = fmaf(accM[1][4*q+1], xq[q].y, pd.y);
                pd.y = fmaf(accM[1][4*q+2], xq[q].z, pd.y);
                pd.y = fmaf(accM[1][4*q+3], xq[q].w, pd.y);
                pd.z = fmaf(accM[2][4*q+0], xq[q].x, pd.z);
                pd.z = fmaf(accM[2][4*q+1], xq[q].y, pd.z);
                pd.z = fmaf(accM[2][4*q+2], xq[q].z, pd.z);
                pd.z = fmaf(accM[2][4*q+3], xq[q].w, pd.z);
                pd.w = fmaf(accM[3][4*q+0], xq[q].x, pd.w);
                pd.w = fmaf(accM[3][4*q+1], xq[q].y, pd.w);
                pd.w = fmaf(accM[3][4*q+2], xq[q].z, pd.w);
                pd.w = fmaf(accM[3][4*q+3], xq[q].w, pd.w);
            }

            #pragma unroll
            for (int off = 32; off; off >>= 1) {
                pd.x += __shfl_xor(pd.x, off);
                pd.y += __shfl_xor(pd.y, off);
                pd.z += __shfl_xor(pd.z, off);
                pd.w += __shfl_xor(pd.w, off);
            }
            if (lane == 0) {
                red[cgp][rq * 4 + 0] = pd.x;
                red[cgp][rq * 4 + 1] = pd.y;
                red[cgp][rq * 4 + 2] = pd.z;
                red[cgp][rq * 4 + 3] = pd.w;
            }
            __syncthreads();                   // (B) red ready

            // producers = lanes 0..15 of wave 0; thread0's vmcnt(0) drains
            // this wave's stores -> no separate barrier-entry sync needed
            if (tid < 16) {
                const float y = red[0][tid] + red[1][tid]
                              + red[2][tid] + red[3][tid];
                const float g = cw[tid] + RHO_C * (y - wl[tid]);
                float xn = xs[blk * 16 + tid] - STEP_C * g;
                xn = xn > 0.f ? xn : 0.f;
                astore(&xdst[blk * 16 + tid], xn);
            }
            if (tid == 0)
                chain_notify_wait(bstate, xcc, leafT, rootT, bar_n);
            ++bar_n;
            __syncthreads();                   // (C) release
        }
        // INNER_C even -> final x is in x0

        // ---- Ax on own 8 rows + s,u,rt update (block-local) ----
        {
            float2 lo = aload2(x0 + 4 * tid);
            float2 hi = aload2(x0 + 4 * tid + 2);
            xs4[tid] = make_float4(lo.x, lo.y, hi.x, hi.y);
        }
        __syncthreads();
        {
            const int r = blk * 8 + (wave >> 1), h = wave & 1;
            const float4* Ar = A4 + (size_t)r * 1024 + h * 512;
            const float4* xh = xs4 + h * 512;
            float4 acc = {0.f, 0.f, 0.f, 0.f};
            #pragma unroll
            for (int it = 0; it < 8; ++it) {
                float4 a = Ar[it * 64 + lane], xv = xh[it * 64 + lane];
                acc.x = fmaf(a.x, xv.x, acc.x); acc.y = fmaf(a.y, xv.y, acc.y);
                acc.z = fmaf(a.z, xv.z, acc.z); acc.w = fmaf(a.w, xv.w, acc.w);
            }
            float d = acc.x + acc.y + acc.z + acc.w;
            #pragma unroll
            for (int off = 32; off; off >>= 1) d += __shfl_xor(d, off);
            if (lane == 0) tpart[wave] = d;
        }
        __syncthreads();                       // tpart ready
        if (tid < 8) {
            const int i = blk * 8 + tid;
            const float a  = tpart[2 * tid] + tpart[2 * tid + 1];
            const float bb = bvec[i];
            const float uu = uv[tid];
            float sn = a - bb + uu; sn = sn > 0.f ? sn : 0.f;
            const float un = uu + a - sn - bb;
            sv[tid] = sn; uv[tid] = un;
            astore(&rt[i], sn + bb - un);
        }
        if (tid == 0)
            chain_notify_wait(bstate, xcc, leafT, rootT, bar_n);
        ++bar_n;
        __syncthreads();                       // release
    }

    // ---- outputs: [x(4096), s(2048), u(2048), -u(2048)] ----
    if (tid < 16) out[blk * 16 + tid] = aload(&x0[blk * 16 + tid]);
    if (tid < 8) {
        const int i = blk * 8 + tid;
        out[4096 + i] = sv[tid];
        out[6144 + i] = uv[tid];
        out[8192 + i] = -uv[tid];
    }
}

extern "C" void kernel_launch(void* const* d_in, const int* in_sizes, int n_in,
                              void* d_out, int out_size, void* d_ws, size_t ws_size,
                              hipStream_t stream) {
    const float* A    = (const float*)d_in[0];   // 2048*4096
    const float* bvec = (const float*)d_in[1];   // 2048
    const float* cvec = (const float*)d_in[2];   // 4096
    float* out = (float*)d_out;

    float* ws = (float*)d_ws;
    float* x0 = ws;                    // 4096
    float* x1 = ws + 4096;             // 4096
    float* rt = ws + 8192;             // 2048
    unsigned* bstate = (unsigned*)(ws + 12288);  // 512 uints

    void* args[] = { (void*)&A, (void*)&bvec, (void*)&cvec, (void*)&out,
                     (void*)&x0, (void*)&x1, (void*)&rt, (void*)&bstate };
    hipError_t err = hipLaunchCooperativeKernel((const void*)admm_xcd,
                               dim3(256), dim3(1024), args, 0, stream);
    (void)err;
}

// Round 9
// 10256.656 us; speedup vs baseline: 1.1536x; 1.1536x over previous
//
#include <hip/hip_runtime.h>
#include <hip/hip_cooperative_groups.h>

namespace cg = cooperative_groups;

#define M_ROWS 2048
#define N_COLS 4096
#define RHO_C 1.0f
#define STEP_C 5e-05f
#define MAX_ITERS_C 100
#define INNER_C 20

// Relaxed agent-scope atomics: coherent at the Infinity Cache (sc1 path).
// Session law (R1-R8, 8 bracketing experiments): arrival RMWs spread over
// >=8 lines at AGENT scope (workgroup-scope L2 leaves regressed, R8); the
// POLLED line receives exactly ONE write per round; data exchange is
// read-once agent-scope; pollers back off with s_sleep. R0's fast_barrier
// is the measured optimum of this space — do not touch it.
__device__ __forceinline__ float aload(const float* p) {
    return __hip_atomic_load(p, __ATOMIC_RELAXED, __HIP_MEMORY_SCOPE_AGENT);
}
__device__ __forceinline__ void astore(float* p, float v) {
    __hip_atomic_store(p, v, __ATOMIC_RELAXED, __HIP_MEMORY_SCOPE_AGENT);
}
__device__ __forceinline__ float2 aload2(const float* p) {
    unsigned long long v = __hip_atomic_load(
        (const unsigned long long*)p, __ATOMIC_RELAXED,
        __HIP_MEMORY_SCOPE_AGENT);
    union { unsigned long long u; float2 f; } c; c.u = v; return c.f;
}

// Fence-light 2-level grid barrier. Monotonic counters, no resets.
// Leaves: bs[g*32], g<8 (128 B apart). Root: bs[256]. Epoch: bs[288].
// Pollers watch the EPOCH line only (1 RMW/round on it — quiet regime).
__device__ inline void fast_barrier(unsigned* bs, int blk, unsigned n) {
    __syncthreads();   // each wave drains its own vmcnt before s_barrier
    if (threadIdx.x == 0) {
        __builtin_amdgcn_fence(__ATOMIC_RELEASE, "workgroup");
        unsigned* leaf = bs + ((blk & 7) << 5);
        unsigned* root = bs + 256;
        unsigned* ep   = bs + 288;
        unsigned old = __hip_atomic_fetch_add(leaf, 1u, __ATOMIC_RELAXED,
                                              __HIP_MEMORY_SCOPE_AGENT);
        if (old == n * 32u + 31u) {
            unsigned ro = __hip_atomic_fetch_add(root, 1u, __ATOMIC_RELAXED,
                                                 __HIP_MEMORY_SCOPE_AGENT);
            if (ro == n * 8u + 7u)
                __hip_atomic_fetch_add(ep, 1u, __ATOMIC_RELAXED,
                                       __HIP_MEMORY_SCOPE_AGENT);
        }
        while (__hip_atomic_load(ep, __ATOMIC_RELAXED,
                                 __HIP_MEMORY_SCOPE_AGENT) <= n)
            __builtin_amdgcn_s_sleep(1);
        __builtin_amdgcn_fence(__ATOMIC_ACQUIRE, "workgroup");
    }
    __syncthreads();
}

// 256 blocks (1/CU) x 1024 threads (16 waves), persistent cooperative kernel.
// Gram form: g = c + rho*(M x - A^T rt), M = A^T A held ENTIRELY in registers.
// R9: the block's w-phase A-slice (A[:, 16b..16b+16), 128 KB — constant all
// 100 outers) is cached in LDS once, eliminating 3.2 GB of per-outer HBM
// re-streaming (the dominant FETCH term). LDS budget: 157,184 B of 160 KiB;
// the M-precompute 64 KB staging overlays the cache region (disjoint in time).
__global__ __launch_bounds__(1024) void admm_ldsA(
    const float* __restrict__ A, const float* __restrict__ bvec,
    const float* __restrict__ cvec, float* __restrict__ out,
    float* __restrict__ x0, float* __restrict__ x1,
    float* __restrict__ rt, unsigned* __restrict__ bstate)
{
    cg::grid_group grid = cg::this_grid();
    const int tid  = threadIdx.x;
    const int blk  = blockIdx.x;
    const int lane = tid & 63;
    const int wave = tid >> 6;
    const int cgp  = wave >> 2;   // col-group: cols [1024*cgp, +1024)
    const int rq   = wave & 3;    // row-quad : rows 16*blk + 4*rq .. +4

    __shared__ float4 awbuf4[8192];      // 128 KB: w-slice cache (and precompute staging)
    __shared__ float4 xs4[1024];         // 16 KB staged x (and Ax-phase x)
    __shared__ float  rbuf[2048];        // 8 KB rt gather (w-phase)
    __shared__ float  red[4][16];        // per-colgroup row partials
    __shared__ float4 gred[64];          // w-phase reduce scratch
    __shared__ float  wl[16], cw[16];
    __shared__ float  sv[8], uv[8], tpart[16];

    float* xs = reinterpret_cast<float*>(xs4);
    const float4* A4 = reinterpret_cast<const float4*>(A);
    float*  abuf  = reinterpret_cast<float*>(awbuf4);   // precompute overlay
    float4* abuf4 = awbuf4;

    // ---- init ----
    if (tid < 16) {
        cw[tid] = cvec[blk * 16 + tid];
        astore(&x0[blk * 16 + tid], 0.0f);
    }
    if (tid < 8) {
        sv[tid] = 0.0f; uv[tid] = 0.0f;
        astore(&rt[blk * 8 + tid], bvec[blk * 8 + tid]);
    }
    if (blk == 0 && tid < 320) bstate[tid] = 0u;

    // ---- precompute register-resident M fragment ----
    float accM[4][16];
    #pragma unroll
    for (int r = 0; r < 4; ++r)
        #pragma unroll
        for (int k = 0; k < 16; ++k) accM[r][k] = 0.0f;

    for (int i0 = 0; i0 < M_ROWS; i0 += 4) {
        #pragma unroll
        for (int ii = 0; ii < 4; ++ii)
            abuf4[ii * 1024 + tid] = A4[(size_t)(i0 + ii) * 1024 + tid];
        __syncthreads();
        #pragma unroll
        for (int ii = 0; ii < 4; ++ii) {
            const float*  row  = abuf + ii * N_COLS;
            const float4* row4 = abuf4 + ii * 1024;
            float4 av[4];
            #pragma unroll
            for (int q = 0; q < 4; ++q)
                av[q] = row4[256 * cgp + 64 * q + lane];
            float cb[4];
            #pragma unroll
            for (int r = 0; r < 4; ++r) cb[r] = row[blk * 16 + rq * 4 + r];
            #pragma unroll
            for (int r = 0; r < 4; ++r)
                #pragma unroll
                for (int q = 0; q < 4; ++q) {
                    accM[r][4 * q + 0] = fmaf(cb[r], av[q].x, accM[r][4 * q + 0]);
                    accM[r][4 * q + 1] = fmaf(cb[r], av[q].y, accM[r][4 * q + 1]);
                    accM[r][4 * q + 2] = fmaf(cb[r], av[q].z, accM[r][4 * q + 2]);
                    accM[r][4 * q + 3] = fmaf(cb[r], av[q].w, accM[r][4 * q + 3]);
                }
        }
        __syncthreads();
    }

    // ---- fill persistent w-slice cache (once; constant across outers) ----
    // awbuf4[i*4+gq] = A4[i*1024 + blk*4 + gq]  (row i, this block's 16 cols)
    __syncthreads();   // precompute staging reads done before overwrite
    for (int idx = tid; idx < 8192; idx += 1024)
        awbuf4[idx] = A4[(size_t)(idx >> 2) * 1024 + blk * 4 + (idx & 3)];

    grid.sync();   // single cg sync: publishes x0/rt/bstate (+ block sync)

    // ---- initial x@0 stage (inner-0 of each outer reuses prior stage) ----
    {
        float2 lo = aload2(x0 + 4 * tid);
        float2 hi = aload2(x0 + 4 * tid + 2);
        xs4[tid] = make_float4(lo.x, lo.y, hi.x, hi.y);
    }
    __syncthreads();

    unsigned bar_n = 0;

    for (int outer = 0; outer < MAX_ITERS_C; ++outer) {
        // ---- w-phase (block-local result): wl = (A^T rt)[16b..16b+16) ----
        // rt gather into rbuf (agent-scope, cross-block data); A from LDS cache.
        rbuf[tid]        = aload(&rt[tid]);
        rbuf[tid + 1024] = aload(&rt[tid + 1024]);
        __syncthreads();
        {
            const int p = tid >> 2, gq = tid & 3;
            float4 acc = {0.f, 0.f, 0.f, 0.f};
            #pragma unroll
            for (int k2 = 0; k2 < 8; ++k2) {
                const int i = p + 256 * k2;
                const float tv = rbuf[i];
                float4 a = awbuf4[i * 4 + gq];   // LDS, 2-way aliasing (free)
                acc.x = fmaf(a.x, tv, acc.x); acc.y = fmaf(a.y, tv, acc.y);
                acc.z = fmaf(a.z, tv, acc.z); acc.w = fmaf(a.w, tv, acc.w);
            }
            #pragma unroll
            for (int off = 4; off < 64; off <<= 1) {
                acc.x += __shfl_xor(acc.x, off);
                acc.y += __shfl_xor(acc.y, off);
                acc.z += __shfl_xor(acc.z, off);
                acc.w += __shfl_xor(acc.w, off);
            }
            if ((lane >> 2) == 0) gred[wave * 4 + gq] = acc;
        }
        __syncthreads();
        if (tid < 4) {
            float4 tot = {0.f, 0.f, 0.f, 0.f};
            #pragma unroll
            for (int w = 0; w < 16; ++w) {
                float4 v = gred[w * 4 + tid];
                tot.x += v.x; tot.y += v.y; tot.z += v.z; tot.w += v.w;
            }
            wl[tid * 4 + 0] = tot.x; wl[tid * 4 + 1] = tot.y;
            wl[tid * 4 + 2] = tot.z; wl[tid * 4 + 3] = tot.w;
        }
        __syncthreads();

        // ---- inner PGD: x <- relu(x - step*(c + rho*(Mx - wl))) ----
        for (int inner = 0; inner < INNER_C; ++inner) {
            const float* xsrc = (inner & 1) ? x1 : x0;
            float*       xdst = (inner & 1) ? x0 : x1;

            // coherent vectorized x-exchange: 16 B per thread, once.
            // inner 0: xs4 already holds current x (staged in Ax phase /
            // pre-loop); w-phase no longer touches xs4 -> skip the re-stage.
            if (inner != 0) {
                float2 lo = aload2(xsrc + 4 * tid);
                float2 hi = aload2(xsrc + 4 * tid + 2);
                xs4[tid] = make_float4(lo.x, lo.y, hi.x, hi.y);
                __syncthreads();
            }

            float4 xq[4];
            #pragma unroll
            for (int q = 0; q < 4; ++q)
                xq[q] = xs4[256 * cgp + 64 * q + lane];

            float4 pd = {0.f, 0.f, 0.f, 0.f};
            #pragma unroll
            for (int q = 0; q < 4; ++q) {
                pd.x = fmaf(accM[0][4*q+0], xq[q].x, pd.x);
                pd.x = fmaf(accM[0][4*q+1], xq[q].y, pd.x);
                pd.x = fmaf(accM[0][4*q+2], xq[q].z, pd.x);
                pd.x = fmaf(accM[0][4*q+3], xq[q].w, pd.x);
                pd.y = fmaf(accM[1][4*q+0], xq[q].x, pd.y);
                pd.y = fmaf(accM[1][4*q+1], xq[q].y, pd.y);
                pd.y = fmaf(accM[1][4*q+2], xq[q].z, pd.y);
                pd.y = fmaf(accM[1][4*q+3], xq[q].w, pd.y);
                pd.z = fmaf(accM[2][4*q+0], xq[q].x, pd.z);
                pd.z = fmaf(accM[2][4*q+1], xq[q].y, pd.z);
                pd.z = fmaf(accM[2][4*q+2], xq[q].z, pd.z);
                pd.z = fmaf(accM[2][4*q+3], xq[q].w, pd.z);
                pd.w = fmaf(accM[3][4*q+0], xq[q].x, pd.w);
                pd.w = fmaf(accM[3][4*q+1], xq[q].y, pd.w);
                pd.w = fmaf(accM[3][4*q+2], xq[q].z, pd.w);
                pd.w = fmaf(accM[3][4*q+3], xq[q].w, pd.w);
            }

            #pragma unroll
            for (int off = 32; off; off >>= 1) {
                pd.x += __shfl_xor(pd.x, off);
                pd.y += __shfl_xor(pd.y, off);
                pd.z += __shfl_xor(pd.z, off);
                pd.w += __shfl_xor(pd.w, off);
            }
            if (lane == 0) {
                red[cgp][rq * 4 + 0] = pd.x;
                red[cgp][rq * 4 + 1] = pd.y;
                red[cgp][rq * 4 + 2] = pd.z;
                red[cgp][rq * 4 + 3] = pd.w;
            }
            __syncthreads();

            if (tid < 16) {
                const float y = red[0][tid] + red[1][tid]
                              + red[2][tid] + red[3][tid];
                const float g = cw[tid] + RHO_C * (y - wl[tid]);
                float xn = xs[blk * 16 + tid] - STEP_C * g;
                xn = xn > 0.f ? xn : 0.f;
                astore(&xdst[blk * 16 + tid], xn);
            }
            fast_barrier(bstate, blk, bar_n); ++bar_n;
        }
        // INNER_C even -> final x is in x0

        // ---- Ax on own 8 rows + s,u,rt update (block-local) ----
        {
            float2 lo = aload2(x0 + 4 * tid);
            float2 hi = aload2(x0 + 4 * tid + 2);
            xs4[tid] = make_float4(lo.x, lo.y, hi.x, hi.y);
        }
        __syncthreads();
        {
            const int r = blk * 8 + (wave >> 1), h = wave & 1;
            const float4* Ar = A4 + (size_t)r * 1024 + h * 512;
            const float4* xh = xs4 + h * 512;
            float4 acc = {0.f, 0.f, 0.f, 0.f};
            #pragma unroll
            for (int it = 0; it < 8; ++it) {
                float4 a = Ar[it * 64 + lane], xv = xh[it * 64 + lane];
                acc.x = fmaf(a.x, xv.x, acc.x); acc.y = fmaf(a.y, xv.y, acc.y);
                acc.z = fmaf(a.z, xv.z, acc.z); acc.w = fmaf(a.w, xv.w, acc.w);
            }
            float d = acc.x + acc.y + acc.z + acc.w;
            #pragma unroll
            for (int off = 32; off; off >>= 1) d += __shfl_xor(d, off);
            if (lane == 0) tpart[wave] = d;
        }
        __syncthreads();
        if (tid < 8) {
            const int i = blk * 8 + tid;
            const float a  = tpart[2 * tid] + tpart[2 * tid + 1];
            const float bb = bvec[i];
            const float uu = uv[tid];
            float sn = a - bb + uu; sn = sn > 0.f ? sn : 0.f;
            const float un = uu + a - sn - bb;
            sv[tid] = sn; uv[tid] = un;
            astore(&rt[i], sn + bb - un);
        }
        fast_barrier(bstate, blk, bar_n); ++bar_n;
    }

    // ---- outputs: [x(4096), s(2048), u(2048), -u(2048)] ----
    if (tid < 16) out[blk * 16 + tid] = aload(&x0[blk * 16 + tid]);
    if (tid < 8) {
        const int i = blk * 8 + tid;
        out[4096 + i] = sv[tid];
        out[6144 + i] = uv[tid];
        out[8192 + i] = -uv[tid];
    }
}

extern "C" void kernel_launch(void* const* d_in, const int* in_sizes, int n_in,
                              void* d_out, int out_size, void* d_ws, size_t ws_size,
                              hipStream_t stream) {
    const float* A    = (const float*)d_in[0];   // 2048*4096
    const float* bvec = (const float*)d_in[1];   // 2048
    const float* cvec = (const float*)d_in[2];   // 4096
    float* out = (float*)d_out;

    float* ws = (float*)d_ws;
    float* x0 = ws;                    // 4096
    float* x1 = ws + 4096;             // 4096
    float* rt = ws + 8192;             // 2048
    unsigned* bstate = (unsigned*)(ws + 12288);  // 320 uints

    void* args[] = { (void*)&A, (void*)&bvec, (void*)&cvec, (void*)&out,
                     (void*)&x0, (void*)&x1, (void*)&rt, (void*)&bstate };
    hipError_t err = hipLaunchCooperativeKernel((const void*)admm_ldsA,
                               dim3(256), dim3(1024), args, 0, stream);
    (void)err;
}

// Round 10
// 10220.039 us; speedup vs baseline: 1.1578x; 1.0036x over previous
//
#include <hip/hip_runtime.h>
#include <hip/hip_cooperative_groups.h>

namespace cg = cooperative_groups;

#define M_ROWS 2048
#define N_COLS 4096
#define RHO_C 1.0f
#define STEP_C 5e-05f
#define MAX_ITERS_C 100
#define INNER_C 20

// Relaxed agent-scope atomics: coherent at the Infinity Cache (sc1 path).
// Session law (R1-R8): arrival RMWs spread over >=8 lines at AGENT scope;
// the POLLED line receives exactly ONE write per round; data exchange is
// read-once agent-scope; pollers back off with s_sleep. R0's fast_barrier
// is the measured optimum of this space — do not touch it.
__device__ __forceinline__ float aload(const float* p) {
    return __hip_atomic_load(p, __ATOMIC_RELAXED, __HIP_MEMORY_SCOPE_AGENT);
}
__device__ __forceinline__ void astore(float* p, float v) {
    __hip_atomic_store(p, v, __ATOMIC_RELAXED, __HIP_MEMORY_SCOPE_AGENT);
}
__device__ __forceinline__ float2 aload2(const float* p) {
    unsigned long long v = __hip_atomic_load(
        (const unsigned long long*)p, __ATOMIC_RELAXED,
        __HIP_MEMORY_SCOPE_AGENT);
    union { unsigned long long u; float2 f; } c; c.u = v; return c.f;
}

// Fence-light 2-level grid barrier. Monotonic counters, no resets.
// Leaves: bs[g*32], g<8 (128 B apart). Root: bs[256]. Epoch: bs[288].
// Pollers watch the EPOCH line only (1 RMW/round on it — quiet regime).
__device__ inline void fast_barrier(unsigned* bs, int blk, unsigned n) {
    __syncthreads();   // each wave drains its own vmcnt before s_barrier
    if (threadIdx.x == 0) {
        __builtin_amdgcn_fence(__ATOMIC_RELEASE, "workgroup");
        unsigned* leaf = bs + ((blk & 7) << 5);
        unsigned* root = bs + 256;
        unsigned* ep   = bs + 288;
        unsigned old = __hip_atomic_fetch_add(leaf, 1u, __ATOMIC_RELAXED,
                                              __HIP_MEMORY_SCOPE_AGENT);
        if (old == n * 32u + 31u) {
            unsigned ro = __hip_atomic_fetch_add(root, 1u, __ATOMIC_RELAXED,
                                                 __HIP_MEMORY_SCOPE_AGENT);
            if (ro == n * 8u + 7u)
                __hip_atomic_fetch_add(ep, 1u, __ATOMIC_RELAXED,
                                       __HIP_MEMORY_SCOPE_AGENT);
        }
        while (__hip_atomic_load(ep, __ATOMIC_RELAXED,
                                 __HIP_MEMORY_SCOPE_AGENT) <= n)
            __builtin_amdgcn_s_sleep(1);
        __builtin_amdgcn_fence(__ATOMIC_ACQUIRE, "workgroup");
    }
    __syncthreads();
}

// 256 blocks (1/CU) x 1024 threads (16 waves), persistent cooperative kernel.
// Gram form: g = c + rho*(M x - A^T rt), M = A^T A held ENTIRELY in registers.
// R9: block's w-phase A-slice (128 KB, constant) cached in LDS once.
// R10: block's Ax-phase A-rows (8 rows = 32 floats/thread, constant) held
// in REGISTERS (arx[8] float4) — zero per-outer global A traffic remains.
__global__ __launch_bounds__(1024) void admm_regA(
    const float* __restrict__ A, const float* __restrict__ bvec,
    const float* __restrict__ cvec, float* __restrict__ out,
    float* __restrict__ x0, float* __restrict__ x1,
    float* __restrict__ rt, unsigned* __restrict__ bstate)
{
    cg::grid_group grid = cg::this_grid();
    const int tid  = threadIdx.x;
    const int blk  = blockIdx.x;
    const int lane = tid & 63;
    const int wave = tid >> 6;
    const int cgp  = wave >> 2;   // col-group: cols [1024*cgp, +1024)
    const int rq   = wave & 3;    // row-quad : rows 16*blk + 4*rq .. +4

    __shared__ float4 awbuf4[8192];      // 128 KB: w-slice cache (and precompute staging)
    __shared__ float4 xs4[1024];         // 16 KB staged x (and Ax-phase x)
    __shared__ float  rbuf[2048];        // 8 KB rt gather (w-phase)
    __shared__ float  red[4][16];        // per-colgroup row partials
    __shared__ float4 gred[64];          // w-phase reduce scratch
    __shared__ float  wl[16], cw[16];
    __shared__ float  sv[8], uv[8], tpart[16];

    float* xs = reinterpret_cast<float*>(xs4);
    const float4* A4 = reinterpret_cast<const float4*>(A);
    float*  abuf  = reinterpret_cast<float*>(awbuf4);   // precompute overlay
    float4* abuf4 = awbuf4;

    // ---- init ----
    if (tid < 16) {
        cw[tid] = cvec[blk * 16 + tid];
        astore(&x0[blk * 16 + tid], 0.0f);
    }
    if (tid < 8) {
        sv[tid] = 0.0f; uv[tid] = 0.0f;
        astore(&rt[blk * 8 + tid], bvec[blk * 8 + tid]);
    }
    if (blk == 0 && tid < 320) bstate[tid] = 0u;

    // ---- precompute register-resident M fragment ----
    float accM[4][16];
    #pragma unroll
    for (int r = 0; r < 4; ++r)
        #pragma unroll
        for (int k = 0; k < 16; ++k) accM[r][k] = 0.0f;

    for (int i0 = 0; i0 < M_ROWS; i0 += 4) {
        #pragma unroll
        for (int ii = 0; ii < 4; ++ii)
            abuf4[ii * 1024 + tid] = A4[(size_t)(i0 + ii) * 1024 + tid];
        __syncthreads();
        #pragma unroll
        for (int ii = 0; ii < 4; ++ii) {
            const float*  row  = abuf + ii * N_COLS;
            const float4* row4 = abuf4 + ii * 1024;
            float4 av[4];
            #pragma unroll
            for (int q = 0; q < 4; ++q)
                av[q] = row4[256 * cgp + 64 * q + lane];
            float cb[4];
            #pragma unroll
            for (int r = 0; r < 4; ++r) cb[r] = row[blk * 16 + rq * 4 + r];
            #pragma unroll
            for (int r = 0; r < 4; ++r)
                #pragma unroll
                for (int q = 0; q < 4; ++q) {
                    accM[r][4 * q + 0] = fmaf(cb[r], av[q].x, accM[r][4 * q + 0]);
                    accM[r][4 * q + 1] = fmaf(cb[r], av[q].y, accM[r][4 * q + 1]);
                    accM[r][4 * q + 2] = fmaf(cb[r], av[q].z, accM[r][4 * q + 2]);
                    accM[r][4 * q + 3] = fmaf(cb[r], av[q].w, accM[r][4 * q + 3]);
                }
        }
        __syncthreads();
    }

    // ---- fill persistent w-slice cache (once; constant across outers) ----
    // awbuf4[i*4+gq] = A4[i*1024 + blk*4 + gq]  (row i, this block's 16 cols)
    __syncthreads();   // precompute staging reads done before overwrite
    for (int idx = tid; idx < 8192; idx += 1024)
        awbuf4[idx] = A4[(size_t)(idx >> 2) * 1024 + blk * 4 + (idx & 3)];

    // ---- preload Ax-phase A-rows into registers (constant across outers) ----
    // Ax loop reads exactly Ar[it*64+lane], it=0..7 -> 8 float4 per thread.
    float4 arx[8];
    {
        const int r = blk * 8 + (wave >> 1), h = wave & 1;
        const float4* Ar = A4 + (size_t)r * 1024 + h * 512;
        #pragma unroll
        for (int it = 0; it < 8; ++it)
            arx[it] = Ar[it * 64 + lane];
    }

    grid.sync();   // single cg sync: publishes x0/rt/bstate (+ block sync)

    // ---- initial x@0 stage (inner-0 of each outer reuses prior stage) ----
    {
        float2 lo = aload2(x0 + 4 * tid);
        float2 hi = aload2(x0 + 4 * tid + 2);
        xs4[tid] = make_float4(lo.x, lo.y, hi.x, hi.y);
    }
    __syncthreads();

    unsigned bar_n = 0;

    for (int outer = 0; outer < MAX_ITERS_C; ++outer) {
        // ---- w-phase (block-local result): wl = (A^T rt)[16b..16b+16) ----
        rbuf[tid]        = aload(&rt[tid]);
        rbuf[tid + 1024] = aload(&rt[tid + 1024]);
        __syncthreads();
        {
            const int p = tid >> 2, gq = tid & 3;
            float4 acc = {0.f, 0.f, 0.f, 0.f};
            #pragma unroll
            for (int k2 = 0; k2 < 8; ++k2) {
                const int i = p + 256 * k2;
                const float tv = rbuf[i];
                float4 a = awbuf4[i * 4 + gq];   // LDS, 2-way aliasing (free)
                acc.x = fmaf(a.x, tv, acc.x); acc.y = fmaf(a.y, tv, acc.y);
                acc.z = fmaf(a.z, tv, acc.z); acc.w = fmaf(a.w, tv, acc.w);
            }
            #pragma unroll
            for (int off = 4; off < 64; off <<= 1) {
                acc.x += __shfl_xor(acc.x, off);
                acc.y += __shfl_xor(acc.y, off);
                acc.z += __shfl_xor(acc.z, off);
                acc.w += __shfl_xor(acc.w, off);
            }
            if ((lane >> 2) == 0) gred[wave * 4 + gq] = acc;
        }
        __syncthreads();
        if (tid < 4) {
            float4 tot = {0.f, 0.f, 0.f, 0.f};
            #pragma unroll
            for (int w = 0; w < 16; ++w) {
                float4 v = gred[w * 4 + tid];
                tot.x += v.x; tot.y += v.y; tot.z += v.z; tot.w += v.w;
            }
            wl[tid * 4 + 0] = tot.x; wl[tid * 4 + 1] = tot.y;
            wl[tid * 4 + 2] = tot.z; wl[tid * 4 + 3] = tot.w;
        }
        __syncthreads();

        // ---- inner PGD: x <- relu(x - step*(c + rho*(Mx - wl))) ----
        for (int inner = 0; inner < INNER_C; ++inner) {
            const float* xsrc = (inner & 1) ? x1 : x0;
            float*       xdst = (inner & 1) ? x0 : x1;

            // inner 0: xs4 already holds current x (Ax phase / pre-loop stage)
            if (inner != 0) {
                float2 lo = aload2(xsrc + 4 * tid);
                float2 hi = aload2(xsrc + 4 * tid + 2);
                xs4[tid] = make_float4(lo.x, lo.y, hi.x, hi.y);
                __syncthreads();
            }

            float4 xq[4];
            #pragma unroll
            for (int q = 0; q < 4; ++q)
                xq[q] = xs4[256 * cgp + 64 * q + lane];

            float4 pd = {0.f, 0.f, 0.f, 0.f};
            #pragma unroll
            for (int q = 0; q < 4; ++q) {
                pd.x = fmaf(accM[0][4*q+0], xq[q].x, pd.x);
                pd.x = fmaf(accM[0][4*q+1], xq[q].y, pd.x);
                pd.x = fmaf(accM[0][4*q+2], xq[q].z, pd.x);
                pd.x = fmaf(accM[0][4*q+3], xq[q].w, pd.x);
                pd.y = fmaf(accM[1][4*q+0], xq[q].x, pd.y);
                pd.y = fmaf(accM[1][4*q+1], xq[q].y, pd.y);
                pd.y = fmaf(accM[1][4*q+2], xq[q].z, pd.y);
                pd.y = fmaf(accM[1][4*q+3], xq[q].w, pd.y);
                pd.z = fmaf(accM[2][4*q+0], xq[q].x, pd.z);
                pd.z = fmaf(accM[2][4*q+1], xq[q].y, pd.z);
                pd.z = fmaf(accM[2][4*q+2], xq[q].z, pd.z);
                pd.z = fmaf(accM[2][4*q+3], xq[q].w, pd.z);
                pd.w = fmaf(accM[3][4*q+0], xq[q].x, pd.w);
                pd.w = fmaf(accM[3][4*q+1], xq[q].y, pd.w);
                pd.w = fmaf(accM[3][4*q+2], xq[q].z, pd.w);
                pd.w = fmaf(accM[3][4*q+3], xq[q].w, pd.w);
            }

            #pragma unroll
            for (int off = 32; off; off >>= 1) {
                pd.x += __shfl_xor(pd.x, off);
                pd.y += __shfl_xor(pd.y, off);
                pd.z += __shfl_xor(pd.z, off);
                pd.w += __shfl_xor(pd.w, off);
            }
            if (lane == 0) {
                red[cgp][rq * 4 + 0] = pd.x;
                red[cgp][rq * 4 + 1] = pd.y;
                red[cgp][rq * 4 + 2] = pd.z;
                red[cgp][rq * 4 + 3] = pd.w;
            }
            __syncthreads();

            if (tid < 16) {
                const float y = red[0][tid] + red[1][tid]
                              + red[2][tid] + red[3][tid];
                const float g = cw[tid] + RHO_C * (y - wl[tid]);
                float xn = xs[blk * 16 + tid] - STEP_C * g;
                xn = xn > 0.f ? xn : 0.f;
                astore(&xdst[blk * 16 + tid], xn);
            }
            fast_barrier(bstate, blk, bar_n); ++bar_n;
        }
        // INNER_C even -> final x is in x0

        // ---- Ax on own 8 rows (A from REGISTERS) + s,u,rt update ----
        {
            float2 lo = aload2(x0 + 4 * tid);
            float2 hi = aload2(x0 + 4 * tid + 2);
            xs4[tid] = make_float4(lo.x, lo.y, hi.x, hi.y);
        }
        __syncthreads();
        {
            const int h = wave & 1;
            const float4* xh = xs4 + h * 512;
            float4 acc = {0.f, 0.f, 0.f, 0.f};
            #pragma unroll
            for (int it = 0; it < 8; ++it) {
                float4 a = arx[it], xv = xh[it * 64 + lane];
                acc.x = fmaf(a.x, xv.x, acc.x); acc.y = fmaf(a.y, xv.y, acc.y);
                acc.z = fmaf(a.z, xv.z, acc.z); acc.w = fmaf(a.w, xv.w, acc.w);
            }
            float d = acc.x + acc.y + acc.z + acc.w;
            #pragma unroll
            for (int off = 32; off; off >>= 1) d += __shfl_xor(d, off);
            if (lane == 0) tpart[wave] = d;
        }
        __syncthreads();
        if (tid < 8) {
            const int i = blk * 8 + tid;
            const float a  = tpart[2 * tid] + tpart[2 * tid + 1];
            const float bb = bvec[i];
            const float uu = uv[tid];
            float sn = a - bb + uu; sn = sn > 0.f ? sn : 0.f;
            const float un = uu + a - sn - bb;
            sv[tid] = sn; uv[tid] = un;
            astore(&rt[i], sn + bb - un);
        }
        fast_barrier(bstate, blk, bar_n); ++bar_n;
    }

    // ---- outputs: [x(4096), s(2048), u(2048), -u(2048)] ----
    if (tid < 16) out[blk * 16 + tid] = aload(&x0[blk * 16 + tid]);
    if (tid < 8) {
        const int i = blk * 8 + tid;
        out[4096 + i] = sv[tid];
        out[6144 + i] = uv[tid];
        out[8192 + i] = -uv[tid];
    }
}

extern "C" void kernel_launch(void* const* d_in, const int* in_sizes, int n_in,
                              void* d_out, int out_size, void* d_ws, size_t ws_size,
                              hipStream_t stream) {
    const float* A    = (const float*)d_in[0];   // 2048*4096
    const float* bvec = (const float*)d_in[1];   // 2048
    const float* cvec = (const float*)d_in[2];   // 4096
    float* out = (float*)d_out;

    float* ws = (float*)d_ws;
    float* x0 = ws;                    // 4096
    float* x1 = ws + 4096;             // 4096
    float* rt = ws + 8192;             // 2048
    unsigned* bstate = (unsigned*)(ws + 12288);  // 320 uints

    void* args[] = { (void*)&A, (void*)&bvec, (void*)&cvec, (void*)&out,
                     (void*)&x0, (void*)&x1, (void*)&rt, (void*)&bstate };
    hipError_t err = hipLaunchCooperativeKernel((const void*)admm_regA,
                               dim3(256), dim3(1024), args, 0, stream);
    (void)err;
}